// Round 8
// baseline (225.753 us; speedup 1.0000x reference)
//
#include <hip/hip_runtime.h>

// IntClassifier: sum-pool over L + dead_shift(4) -> int GEMM (i8 dot4, hi/lo split)
// -> dead_shift(11)+clamp -> int8 (as int32). B=256, C=2048, L=512, N=1000
#define BB 256
#define CC 2048
#define LL 512
#define NN 1000
#define FINAL_SHIFT 4
#define FC_SHIFT 11

// GEMM tiling
#define TBB 64       // b per block
#define TNN 128      // n per block
#define BK 64        // k per LDS stage
#define NKQ 16       // BK/4 packed dwords per row
#define ASTR 36      // As row stride: 16 hi + 16 lo + 4 pad
#define WSTR 132     // Ws row stride: 128 + 4 pad

// Pool persistence: 2048 blocks x 16 sweeps; 4 rows per wave per sweep.
#define PBLK 2048
#define RPS  (PBLK * 16)        // rows per sweep: 4 waves x 4 rows x 2048 = 32768
#define PITER (BB * CC / RPS)   // 16 sweeps

typedef int v4i __attribute__((ext_vector_type(4)));

#if __has_builtin(__builtin_amdgcn_sdot4)
#define DOT4(a, b, c) __builtin_amdgcn_sdot4((a), (b), (c), false)
#else
static __device__ __forceinline__ int dot4_fb(int a, int b, int c) {
#pragma unroll
    for (int j = 0; j < 4; ++j) {
        int av = (a << (24 - 8 * j)) >> 24;
        int bv = (b << (24 - 8 * j)) >> 24;
        c += av * bv;
    }
    return c;
}
#define DOT4(a, b, c) dot4_fb((a), (b), (c))
#endif

__device__ __forceinline__ int dead_shift_i(int x, int shift) {
    int thr = 1 << shift;
    int ax = x < 0 ? -x : x;
    x = (ax >= thr) ? x : 0;
    return x >> shift;
}

// byte-pack helpers (byte j of result = k-value 4q+j)
__device__ __forceinline__ int pack_hi(int4 u) {
    return ((u.x >> 6) & 255) | (((u.y >> 6) & 255) << 8) |
           (((u.z >> 6) & 255) << 16) | (((u.w >> 6) & 255) << 24);
}
__device__ __forceinline__ int pack_lo(int4 u) {
    return (u.x & 63) | ((u.y & 63) << 8) | ((u.z & 63) << 16) | ((u.w & 63) << 24);
}
__device__ __forceinline__ int pack_b(int4 u) {
    return (u.x & 255) | ((u.y & 255) << 8) | ((u.z & 255) << 16) | ((u.w & 255) << 24);
}

// ---------------- Stage 1: persistent, pipelined sum-pool ----------------
// Round-8 single-variable probe: PLAIN loads (nt hint removed), else identical
// to round 7. v[8] in flight, __launch_bounds__(256,8) -> 8 blocks/CU, all
// 2048 blocks resident (32 waves/CU). Next sweep's 8 loads issue before the
// current sweep's shfl chain + store.
__global__ __launch_bounds__(256, 8) void pool_kernel(const int* __restrict__ x,
                                                      int* __restrict__ acc) {
    int wave = threadIdx.x >> 6;
    int lane = threadIdx.x & 63;
    int g = lane >> 4;                 // row within wave's quad
    int j = lane & 15;                 // lane within 16-lane row group

    long long rb = (long long)blockIdx.x * 16 + wave * 4;   // first sweep's row base

    v4i v[8];
    {
        const v4i* p = (const v4i*)(x + (rb + g) * (long long)LL + j * 4);
#pragma unroll
        for (int c = 0; c < 8; ++c) v[c] = p[c * 16];
    }

#pragma unroll
    for (int it = 0; it < PITER; ++it) {
        int s = 0;
#pragma unroll
        for (int c = 0; c < 8; ++c) s += v[c].x + v[c].y + v[c].z + v[c].w;

        // issue next sweep's loads before the dependent shfl/store tail
        long long rbn = rb + RPS;
        if (it + 1 < PITER) {
            const v4i* p = (const v4i*)(x + (rbn + g) * (long long)LL + j * 4);
#pragma unroll
            for (int c = 0; c < 8; ++c) v[c] = p[c * 16];
        }

        s += __shfl_xor(s, 1, 64);
        s += __shfl_xor(s, 2, 64);
        s += __shfl_xor(s, 4, 64);
        s += __shfl_xor(s, 8, 64);

        if (j == 0) acc[rb + g] = dead_shift_i(s, FINAL_SHIFT);
        rb = rbn;
    }
}

// ---------------- Stage 2: i8-dot4 GEMM, K-split partials ---- (unchanged) ----
__global__ __launch_bounds__(256) void gemm_kernel(const int* __restrict__ acc,
                                                   const int* __restrict__ w,
                                                   int* __restrict__ partial,
                                                   int kch) {
    __shared__ int As[TBB][ASTR];    // [b][0..15]=hi dwords, [16..31]=lo dwords
    __shared__ int Ws[NKQ][WSTR];    // [kq][n] packed W dwords

    int b0 = blockIdx.x * TBB;
    int n0 = blockIdx.y * TNN;
    int kbase = blockIdx.z * kch;

    int t   = threadIdx.x;
    int tx4 = (t & 15) * 4;
    int ty4 = (t >> 4) * 4;

    int rH[4][8], rL[4][8];
#pragma unroll
    for (int bi = 0; bi < 4; ++bi)
#pragma unroll
        for (int j = 0; j < 8; ++j) { rH[bi][j] = 0; rL[bi][j] = 0; }

    for (int k0 = kbase; k0 < kbase + kch; k0 += BK) {
        {
            int b   = t >> 2;
            int kq0 = (t & 3) * 4;
            const int* src = acc + (long long)(b0 + b) * CC + k0 + kq0 * 4;
            int4 u0 = *(const int4*)(src + 0);
            int4 u1 = *(const int4*)(src + 4);
            int4 u2 = *(const int4*)(src + 8);
            int4 u3 = *(const int4*)(src + 12);
            *(int4*)&As[b][kq0]      = make_int4(pack_hi(u0), pack_hi(u1), pack_hi(u2), pack_hi(u3));
            *(int4*)&As[b][16 + kq0] = make_int4(pack_lo(u0), pack_lo(u1), pack_lo(u2), pack_lo(u3));
        }
        {
            int jq = t & 15;
            int ng = t >> 4;
#pragma unroll
            for (int rep = 0; rep < 8; ++rep) {
                int n  = rep * 16 + ng;
                int nn = n0 + n;
                int4 u = make_int4(0, 0, 0, 0);
                if (nn < NN) u = *(const int4*)(w + (long long)nn * CC + k0 + jq * 4);
                Ws[jq][n] = pack_b(u);
            }
        }
        __syncthreads();

#pragma unroll
        for (int q4 = 0; q4 < NKQ; q4 += 4) {
            int4 aH[4], aL[4];
#pragma unroll
            for (int bi = 0; bi < 4; ++bi) {
                aH[bi] = *(const int4*)&As[ty4 + bi][q4];
                aL[bi] = *(const int4*)&As[ty4 + bi][16 + q4];
            }
#pragma unroll
            for (int q = 0; q < 4; ++q) {
                int4 w0 = *(const int4*)&Ws[q4 + q][tx4];
                int4 w1 = *(const int4*)&Ws[q4 + q][64 + tx4];
#pragma unroll
                for (int bi = 0; bi < 4; ++bi) {
                    int ah = (q == 0) ? aH[bi].x : (q == 1) ? aH[bi].y
                           : (q == 2) ? aH[bi].z : aH[bi].w;
                    int al = (q == 0) ? aL[bi].x : (q == 1) ? aL[bi].y
                           : (q == 2) ? aL[bi].z : aL[bi].w;
                    rH[bi][0] = DOT4(ah, w0.x, rH[bi][0]);
                    rH[bi][1] = DOT4(ah, w0.y, rH[bi][1]);
                    rH[bi][2] = DOT4(ah, w0.z, rH[bi][2]);
                    rH[bi][3] = DOT4(ah, w0.w, rH[bi][3]);
                    rH[bi][4] = DOT4(ah, w1.x, rH[bi][4]);
                    rH[bi][5] = DOT4(ah, w1.y, rH[bi][5]);
                    rH[bi][6] = DOT4(ah, w1.z, rH[bi][6]);
                    rH[bi][7] = DOT4(ah, w1.w, rH[bi][7]);
                    rL[bi][0] = DOT4(al, w0.x, rL[bi][0]);
                    rL[bi][1] = DOT4(al, w0.y, rL[bi][1]);
                    rL[bi][2] = DOT4(al, w0.z, rL[bi][2]);
                    rL[bi][3] = DOT4(al, w0.w, rL[bi][3]);
                    rL[bi][4] = DOT4(al, w1.x, rL[bi][4]);
                    rL[bi][5] = DOT4(al, w1.y, rL[bi][5]);
                    rL[bi][6] = DOT4(al, w1.z, rL[bi][6]);
                    rL[bi][7] = DOT4(al, w1.w, rL[bi][7]);
                }
            }
        }
        __syncthreads();
    }

    long long base = (long long)blockIdx.z * BB * NN;
#pragma unroll
    for (int bi = 0; bi < 4; ++bi) {
        int b = b0 + ty4 + bi;
#pragma unroll
        for (int j = 0; j < 8; ++j) {
            int n = n0 + ((j < 4) ? (tx4 + j) : (64 + tx4 + (j - 4)));
            if (n < NN)
                partial[base + (long long)b * NN + n] = (rH[bi][j] << 6) + rL[bi][j];
        }
    }
}

// ---------------- Stage 3: reduce K-splits, dead_shift(11), clamp ----------------
__global__ __launch_bounds__(256) void epilogue_kernel(const int* __restrict__ partial,
                                                       int* __restrict__ out, int z) {
    int idx = blockIdx.x * 256 + threadIdx.x;
    if (idx >= BB * NN) return;
    int s = 0;
    for (int i = 0; i < z; ++i) s += partial[(long long)i * BB * NN + idx];
    int v = dead_shift_i(s, FC_SHIFT);
    v = min(127, max(-128, v));
    out[idx] = v;
}

extern "C" void kernel_launch(void* const* d_in, const int* in_sizes, int n_in,
                              void* d_out, int out_size, void* d_ws, size_t ws_size,
                              hipStream_t stream) {
    const int* x = (const int*)d_in[0];     // (B, C, L) int32
    const int* w = (const int*)d_in[1];     // (N, C) int32
    int* out = (int*)d_out;                 // (B, N) int32 values in [-128,127]

    int* acc     = (int*)d_ws;              // B*C ints = 2 MB
    int* partial = acc + (size_t)BB * CC;   // Z*B*N ints

    size_t accBytes = (size_t)BB * CC * 4;
    int Z = 8;                              // 10 MB total ws
    while (Z > 1 && ws_size < accBytes + (size_t)Z * BB * NN * 4) Z >>= 1;
    int kch = CC / Z;

    pool_kernel<<<PBLK, 256, 0, stream>>>(x, acc);

    dim3 g2(BB / TBB, (NN + TNN - 1) / TNN, Z);   // (4, 8, Z) = 256 blocks at Z=8
    gemm_kernel<<<g2, 256, 0, stream>>>(acc, w, partial, kch);

    epilogue_kernel<<<(BB * NN + 255) / 256, 256, 0, stream>>>(partial, out, Z);
}

// Round 9
// 209.362 us; speedup vs baseline: 1.0783x; 1.0783x over previous
//
#include <hip/hip_runtime.h>

// IntClassifier: sum-pool over L + dead_shift(4) -> int GEMM (i8 dot4, hi/lo split)
// -> dead_shift(11)+clamp -> int8 (as int32). B=256, C=2048, L=512, N=1000
#define BB 256
#define CC 2048
#define LL 512
#define NN 1000
#define FINAL_SHIFT 4
#define FC_SHIFT 11

// GEMM tiling
#define TBB 64       // b per block
#define TNN 128      // n per block
#define BK 64        // k per LDS stage
#define NKQ 16       // BK/4 packed dwords per row
#define ASTR 36      // As row stride: 16 hi + 16 lo + 4 pad
#define WSTR 132     // Ws row stride: 128 + 4 pad

// Pool persistence: 2048 blocks; each block owns 256 contiguous rows (512 KB)
// and walks them sequentially across 16 sweeps (16 rows per block per sweep).
#define PBLK 2048
#define RPB  (BB * CC / PBLK)   // rows per block = 256
#define PITER 16                // sweeps (16 rows each)

typedef int v4i __attribute__((ext_vector_type(4)));

#if __has_builtin(__builtin_amdgcn_sdot4)
#define DOT4(a, b, c) __builtin_amdgcn_sdot4((a), (b), (c), false)
#else
static __device__ __forceinline__ int dot4_fb(int a, int b, int c) {
#pragma unroll
    for (int j = 0; j < 4; ++j) {
        int av = (a << (24 - 8 * j)) >> 24;
        int bv = (b << (24 - 8 * j)) >> 24;
        c += av * bv;
    }
    return c;
}
#define DOT4(a, b, c) dot4_fb((a), (b), (c))
#endif

__device__ __forceinline__ int dead_shift_i(int x, int shift) {
    int thr = 1 << shift;
    int ax = x < 0 ? -x : x;
    x = (ax >= thr) ? x : 0;
    return x >> shift;
}

// byte-pack helpers (byte j of result = k-value 4q+j)
__device__ __forceinline__ int pack_hi(int4 u) {
    return ((u.x >> 6) & 255) | (((u.y >> 6) & 255) << 8) |
           (((u.z >> 6) & 255) << 16) | (((u.w >> 6) & 255) << 24);
}
__device__ __forceinline__ int pack_lo(int4 u) {
    return (u.x & 63) | ((u.y & 63) << 8) | ((u.z & 63) << 16) | ((u.w & 63) << 24);
}
__device__ __forceinline__ int pack_b(int4 u) {
    return (u.x & 255) | ((u.y & 255) << 8) | ((u.z & 255) << 16) | ((u.w & 255) << 24);
}

// ---------------- Stage 1: persistent, pipelined sum-pool ----------------
// nt loads RESTORED (round-8 ablation: removing nt cost +26us — evict-first
// keeps the 1GB stream from thrashing L2/L3). Round-9 single variable: each
// block walks a CONTIGUOUS 512KB region sequentially (DRAM page locality)
// instead of 64MB grid-wide sweep jumps. v[8] in flight, bounds(256,8) ->
// 8 blocks/CU, all 2048 blocks resident.
__global__ __launch_bounds__(256, 8) void pool_kernel(const int* __restrict__ x,
                                                      int* __restrict__ acc) {
    int wave = threadIdx.x >> 6;
    int lane = threadIdx.x & 63;
    int g = lane >> 4;                 // row within wave's quad
    int j = lane & 15;                 // lane within 16-lane row group

    long long rb = (long long)blockIdx.x * RPB + wave * 4;  // sweep 0 row base

    v4i v[8];
    {
        const int* p = x + (rb + g) * (long long)LL + j * 4;
#pragma unroll
        for (int c = 0; c < 8; ++c) v[c] = __builtin_nontemporal_load((const v4i*)(p + c * 64));
    }

#pragma unroll
    for (int it = 0; it < PITER; ++it) {
        int s = 0;
#pragma unroll
        for (int c = 0; c < 8; ++c) s += v[c].x + v[c].y + v[c].z + v[c].w;

        // issue next sweep's loads before the dependent shfl/store tail
        long long rbn = rb + 16;       // next 16 contiguous rows of this block
        if (it + 1 < PITER) {
            const int* p = x + (rbn + g) * (long long)LL + j * 4;
#pragma unroll
            for (int c = 0; c < 8; ++c) v[c] = __builtin_nontemporal_load((const v4i*)(p + c * 64));
        }

        s += __shfl_xor(s, 1, 64);
        s += __shfl_xor(s, 2, 64);
        s += __shfl_xor(s, 4, 64);
        s += __shfl_xor(s, 8, 64);

        if (j == 0) acc[rb + g] = dead_shift_i(s, FINAL_SHIFT);
        rb = rbn;
    }
}

// ---------------- Stage 2: i8-dot4 GEMM, K-split partials ---- (unchanged) ----
__global__ __launch_bounds__(256) void gemm_kernel(const int* __restrict__ acc,
                                                   const int* __restrict__ w,
                                                   int* __restrict__ partial,
                                                   int kch) {
    __shared__ int As[TBB][ASTR];    // [b][0..15]=hi dwords, [16..31]=lo dwords
    __shared__ int Ws[NKQ][WSTR];    // [kq][n] packed W dwords

    int b0 = blockIdx.x * TBB;
    int n0 = blockIdx.y * TNN;
    int kbase = blockIdx.z * kch;

    int t   = threadIdx.x;
    int tx4 = (t & 15) * 4;
    int ty4 = (t >> 4) * 4;

    int rH[4][8], rL[4][8];
#pragma unroll
    for (int bi = 0; bi < 4; ++bi)
#pragma unroll
        for (int j = 0; j < 8; ++j) { rH[bi][j] = 0; rL[bi][j] = 0; }

    for (int k0 = kbase; k0 < kbase + kch; k0 += BK) {
        {
            int b   = t >> 2;
            int kq0 = (t & 3) * 4;
            const int* src = acc + (long long)(b0 + b) * CC + k0 + kq0 * 4;
            int4 u0 = *(const int4*)(src + 0);
            int4 u1 = *(const int4*)(src + 4);
            int4 u2 = *(const int4*)(src + 8);
            int4 u3 = *(const int4*)(src + 12);
            *(int4*)&As[b][kq0]      = make_int4(pack_hi(u0), pack_hi(u1), pack_hi(u2), pack_hi(u3));
            *(int4*)&As[b][16 + kq0] = make_int4(pack_lo(u0), pack_lo(u1), pack_lo(u2), pack_lo(u3));
        }
        {
            int jq = t & 15;
            int ng = t >> 4;
#pragma unroll
            for (int rep = 0; rep < 8; ++rep) {
                int n  = rep * 16 + ng;
                int nn = n0 + n;
                int4 u = make_int4(0, 0, 0, 0);
                if (nn < NN) u = *(const int4*)(w + (long long)nn * CC + k0 + jq * 4);
                Ws[jq][n] = pack_b(u);
            }
        }
        __syncthreads();

#pragma unroll
        for (int q4 = 0; q4 < NKQ; q4 += 4) {
            int4 aH[4], aL[4];
#pragma unroll
            for (int bi = 0; bi < 4; ++bi) {
                aH[bi] = *(const int4*)&As[ty4 + bi][q4];
                aL[bi] = *(const int4*)&As[ty4 + bi][16 + q4];
            }
#pragma unroll
            for (int q = 0; q < 4; ++q) {
                int4 w0 = *(const int4*)&Ws[q4 + q][tx4];
                int4 w1 = *(const int4*)&Ws[q4 + q][64 + tx4];
#pragma unroll
                for (int bi = 0; bi < 4; ++bi) {
                    int ah = (q == 0) ? aH[bi].x : (q == 1) ? aH[bi].y
                           : (q == 2) ? aH[bi].z : aH[bi].w;
                    int al = (q == 0) ? aL[bi].x : (q == 1) ? aL[bi].y
                           : (q == 2) ? aL[bi].z : aL[bi].w;
                    rH[bi][0] = DOT4(ah, w0.x, rH[bi][0]);
                    rH[bi][1] = DOT4(ah, w0.y, rH[bi][1]);
                    rH[bi][2] = DOT4(ah, w0.z, rH[bi][2]);
                    rH[bi][3] = DOT4(ah, w0.w, rH[bi][3]);
                    rH[bi][4] = DOT4(ah, w1.x, rH[bi][4]);
                    rH[bi][5] = DOT4(ah, w1.y, rH[bi][5]);
                    rH[bi][6] = DOT4(ah, w1.z, rH[bi][6]);
                    rH[bi][7] = DOT4(ah, w1.w, rH[bi][7]);
                    rL[bi][0] = DOT4(al, w0.x, rL[bi][0]);
                    rL[bi][1] = DOT4(al, w0.y, rL[bi][1]);
                    rL[bi][2] = DOT4(al, w0.z, rL[bi][2]);
                    rL[bi][3] = DOT4(al, w0.w, rL[bi][3]);
                    rL[bi][4] = DOT4(al, w1.x, rL[bi][4]);
                    rL[bi][5] = DOT4(al, w1.y, rL[bi][5]);
                    rL[bi][6] = DOT4(al, w1.z, rL[bi][6]);
                    rL[bi][7] = DOT4(al, w1.w, rL[bi][7]);
                }
            }
        }
        __syncthreads();
    }

    long long base = (long long)blockIdx.z * BB * NN;
#pragma unroll
    for (int bi = 0; bi < 4; ++bi) {
        int b = b0 + ty4 + bi;
#pragma unroll
        for (int j = 0; j < 8; ++j) {
            int n = n0 + ((j < 4) ? (tx4 + j) : (64 + tx4 + (j - 4)));
            if (n < NN)
                partial[base + (long long)b * NN + n] = (rH[bi][j] << 6) + rL[bi][j];
        }
    }
}

// ---------------- Stage 3: reduce K-splits, dead_shift(11), clamp ----------------
__global__ __launch_bounds__(256) void epilogue_kernel(const int* __restrict__ partial,
                                                       int* __restrict__ out, int z) {
    int idx = blockIdx.x * 256 + threadIdx.x;
    if (idx >= BB * NN) return;
    int s = 0;
    for (int i = 0; i < z; ++i) s += partial[(long long)i * BB * NN + idx];
    int v = dead_shift_i(s, FC_SHIFT);
    v = min(127, max(-128, v));
    out[idx] = v;
}

extern "C" void kernel_launch(void* const* d_in, const int* in_sizes, int n_in,
                              void* d_out, int out_size, void* d_ws, size_t ws_size,
                              hipStream_t stream) {
    const int* x = (const int*)d_in[0];     // (B, C, L) int32
    const int* w = (const int*)d_in[1];     // (N, C) int32
    int* out = (int*)d_out;                 // (B, N) int32 values in [-128,127]

    int* acc     = (int*)d_ws;              // B*C ints = 2 MB
    int* partial = acc + (size_t)BB * CC;   // Z*B*N ints

    size_t accBytes = (size_t)BB * CC * 4;
    int Z = 8;                              // 10 MB total ws
    while (Z > 1 && ws_size < accBytes + (size_t)Z * BB * NN * 4) Z >>= 1;
    int kch = CC / Z;

    pool_kernel<<<PBLK, 256, 0, stream>>>(x, acc);

    dim3 g2(BB / TBB, (NN + TNN - 1) / TNN, Z);   // (4, 8, Z) = 256 blocks at Z=8
    gemm_kernel<<<g2, 256, 0, stream>>>(acc, w, partial, kch);

    epilogue_kernel<<<(BB * NN + 255) / 256, 256, 0, stream>>>(partial, out, Z);
}

// Round 10
// 206.642 us; speedup vs baseline: 1.0925x; 1.0132x over previous
//
#include <hip/hip_runtime.h>

// IntClassifier: sum-pool over L + dead_shift(4) -> int GEMM (i8 dot4, hi/lo split)
// -> dead_shift(11)+clamp -> int8 (as int32). B=256, C=2048, L=512, N=1000
#define BB 256
#define CC 2048
#define LL 512
#define NN 1000
#define FINAL_SHIFT 4
#define FC_SHIFT 11

// GEMM tiling
#define TBB 64       // b per block
#define TNN 128      // n per block
#define BK 64        // k per LDS stage
#define NKQ 16       // BK/4 packed dwords per row
#define ASTR 36      // As row stride: 16 hi + 16 lo + 4 pad
#define WSTR 132     // Ws row stride: 128 + 4 pad

// Pool persistence: 2048 blocks x 16 sweeps; 4 rows per wave per sweep.
// GRID-WIDE sweep pattern (round 7): blocks interleave at 32KB, sweeps jump
// 64MB. Measured better than contiguous-per-block walking (r9: +9.6us).
#define PBLK 2048
#define RPS  (PBLK * 16)        // rows per sweep: 4 waves x 4 rows x 2048 = 32768
#define PITER (BB * CC / RPS)   // 16 sweeps

typedef int v4i __attribute__((ext_vector_type(4)));

#if __has_builtin(__builtin_amdgcn_sdot4)
#define DOT4(a, b, c) __builtin_amdgcn_sdot4((a), (b), (c), false)
#else
static __device__ __forceinline__ int dot4_fb(int a, int b, int c) {
#pragma unroll
    for (int j = 0; j < 4; ++j) {
        int av = (a << (24 - 8 * j)) >> 24;
        int bv = (b << (24 - 8 * j)) >> 24;
        c += av * bv;
    }
    return c;
}
#define DOT4(a, b, c) dot4_fb((a), (b), (c))
#endif

__device__ __forceinline__ int dead_shift_i(int x, int shift) {
    int thr = 1 << shift;
    int ax = x < 0 ? -x : x;
    x = (ax >= thr) ? x : 0;
    return x >> shift;
}

// byte-pack helpers (byte j of result = k-value 4q+j)
__device__ __forceinline__ int pack_hi(int4 u) {
    return ((u.x >> 6) & 255) | (((u.y >> 6) & 255) << 8) |
           (((u.z >> 6) & 255) << 16) | (((u.w >> 6) & 255) << 24);
}
__device__ __forceinline__ int pack_lo(int4 u) {
    return (u.x & 63) | ((u.y & 63) << 8) | ((u.z & 63) << 16) | ((u.w & 63) << 24);
}
__device__ __forceinline__ int pack_b4(v4i u) {
    return (u.x & 255) | ((u.y & 255) << 8) | ((u.z & 255) << 16) | ((u.w & 255) << 24);
}

// ---------------- Stage 1: persistent, pipelined sum-pool (round 7 exact) ----
// nt loads (evict-first; removing them cost +26us in r8). v[8] in flight,
// __launch_bounds__(256,8) -> 8 blocks/CU, all 2048 blocks resident
// (32 waves/CU). Next sweep's 8 loads issue before the shfl chain + store.
__global__ __launch_bounds__(256, 8) void pool_kernel(const int* __restrict__ x,
                                                      int* __restrict__ acc) {
    int wave = threadIdx.x >> 6;
    int lane = threadIdx.x & 63;
    int g = lane >> 4;                 // row within wave's quad
    int j = lane & 15;                 // lane within 16-lane row group

    long long rb = (long long)blockIdx.x * 16 + wave * 4;   // first sweep's row base

    v4i v[8];
    {
        const int* p = x + (rb + g) * (long long)LL + j * 4;
#pragma unroll
        for (int c = 0; c < 8; ++c) v[c] = __builtin_nontemporal_load((const v4i*)(p + c * 64));
    }

#pragma unroll
    for (int it = 0; it < PITER; ++it) {
        int s = 0;
#pragma unroll
        for (int c = 0; c < 8; ++c) s += v[c].x + v[c].y + v[c].z + v[c].w;

        // issue next sweep's loads before the dependent shfl/store tail
        long long rbn = rb + RPS;
        if (it + 1 < PITER) {
            const int* p = x + (rbn + g) * (long long)LL + j * 4;
#pragma unroll
            for (int c = 0; c < 8; ++c) v[c] = __builtin_nontemporal_load((const v4i*)(p + c * 64));
        }

        s += __shfl_xor(s, 1, 64);
        s += __shfl_xor(s, 2, 64);
        s += __shfl_xor(s, 4, 64);
        s += __shfl_xor(s, 8, 64);

        if (j == 0) acc[rb + g] = dead_shift_i(s, FINAL_SHIFT);
        rb = rbn;
    }
}

// ---------------- Stage 2: i8-dot4 GEMM, K-split partials ----------------
// Round-10 tweak: W loads via nt (8MB, read-once, streaming).
__global__ __launch_bounds__(256) void gemm_kernel(const int* __restrict__ acc,
                                                   const int* __restrict__ w,
                                                   int* __restrict__ partial,
                                                   int kch) {
    __shared__ int As[TBB][ASTR];    // [b][0..15]=hi dwords, [16..31]=lo dwords
    __shared__ int Ws[NKQ][WSTR];    // [kq][n] packed W dwords

    int b0 = blockIdx.x * TBB;
    int n0 = blockIdx.y * TNN;
    int kbase = blockIdx.z * kch;

    int t   = threadIdx.x;
    int tx4 = (t & 15) * 4;
    int ty4 = (t >> 4) * 4;

    int rH[4][8], rL[4][8];
#pragma unroll
    for (int bi = 0; bi < 4; ++bi)
#pragma unroll
        for (int j = 0; j < 8; ++j) { rH[bi][j] = 0; rL[bi][j] = 0; }

    for (int k0 = kbase; k0 < kbase + kch; k0 += BK) {
        {
            int b   = t >> 2;
            int kq0 = (t & 3) * 4;
            const int* src = acc + (long long)(b0 + b) * CC + k0 + kq0 * 4;
            int4 u0 = *(const int4*)(src + 0);
            int4 u1 = *(const int4*)(src + 4);
            int4 u2 = *(const int4*)(src + 8);
            int4 u3 = *(const int4*)(src + 12);
            *(int4*)&As[b][kq0]      = make_int4(pack_hi(u0), pack_hi(u1), pack_hi(u2), pack_hi(u3));
            *(int4*)&As[b][16 + kq0] = make_int4(pack_lo(u0), pack_lo(u1), pack_lo(u2), pack_lo(u3));
        }
        {
            int jq = t & 15;
            int ng = t >> 4;
#pragma unroll
            for (int rep = 0; rep < 8; ++rep) {
                int n  = rep * 16 + ng;
                int nn = n0 + n;
                v4i u = {0, 0, 0, 0};
                if (nn < NN)
                    u = __builtin_nontemporal_load((const v4i*)(w + (long long)nn * CC + k0 + jq * 4));
                Ws[jq][n] = pack_b4(u);
            }
        }
        __syncthreads();

#pragma unroll
        for (int q4 = 0; q4 < NKQ; q4 += 4) {
            int4 aH[4], aL[4];
#pragma unroll
            for (int bi = 0; bi < 4; ++bi) {
                aH[bi] = *(const int4*)&As[ty4 + bi][q4];
                aL[bi] = *(const int4*)&As[ty4 + bi][16 + q4];
            }
#pragma unroll
            for (int q = 0; q < 4; ++q) {
                int4 w0 = *(const int4*)&Ws[q4 + q][tx4];
                int4 w1 = *(const int4*)&Ws[q4 + q][64 + tx4];
#pragma unroll
                for (int bi = 0; bi < 4; ++bi) {
                    int ah = (q == 0) ? aH[bi].x : (q == 1) ? aH[bi].y
                           : (q == 2) ? aH[bi].z : aH[bi].w;
                    int al = (q == 0) ? aL[bi].x : (q == 1) ? aL[bi].y
                           : (q == 2) ? aL[bi].z : aL[bi].w;
                    rH[bi][0] = DOT4(ah, w0.x, rH[bi][0]);
                    rH[bi][1] = DOT4(ah, w0.y, rH[bi][1]);
                    rH[bi][2] = DOT4(ah, w0.z, rH[bi][2]);
                    rH[bi][3] = DOT4(ah, w0.w, rH[bi][3]);
                    rH[bi][4] = DOT4(ah, w1.x, rH[bi][4]);
                    rH[bi][5] = DOT4(ah, w1.y, rH[bi][5]);
                    rH[bi][6] = DOT4(ah, w1.z, rH[bi][6]);
                    rH[bi][7] = DOT4(ah, w1.w, rH[bi][7]);
                    rL[bi][0] = DOT4(al, w0.x, rL[bi][0]);
                    rL[bi][1] = DOT4(al, w0.y, rL[bi][1]);
                    rL[bi][2] = DOT4(al, w0.z, rL[bi][2]);
                    rL[bi][3] = DOT4(al, w0.w, rL[bi][3]);
                    rL[bi][4] = DOT4(al, w1.x, rL[bi][4]);
                    rL[bi][5] = DOT4(al, w1.y, rL[bi][5]);
                    rL[bi][6] = DOT4(al, w1.z, rL[bi][6]);
                    rL[bi][7] = DOT4(al, w1.w, rL[bi][7]);
                }
            }
        }
        __syncthreads();
    }

    long long base = (long long)blockIdx.z * BB * NN;
#pragma unroll
    for (int bi = 0; bi < 4; ++bi) {
        int b = b0 + ty4 + bi;
#pragma unroll
        for (int j = 0; j < 8; ++j) {
            int n = n0 + ((j < 4) ? (tx4 + j) : (64 + tx4 + (j - 4)));
            if (n < NN)
                partial[base + (long long)b * NN + n] = (rH[bi][j] << 6) + rL[bi][j];
        }
    }
}

// ---------------- Stage 3: reduce K-splits, dead_shift(11), clamp ----------------
// Round-10 tweak: partial loads via nt (read-once streaming).
__global__ __launch_bounds__(256) void epilogue_kernel(const int* __restrict__ partial,
                                                       int* __restrict__ out, int z) {
    int idx = blockIdx.x * 256 + threadIdx.x;
    if (idx >= BB * NN) return;
    int s = 0;
    for (int i = 0; i < z; ++i)
        s += __builtin_nontemporal_load(partial + (long long)i * BB * NN + idx);
    int v = dead_shift_i(s, FC_SHIFT);
    v = min(127, max(-128, v));
    out[idx] = v;
}

extern "C" void kernel_launch(void* const* d_in, const int* in_sizes, int n_in,
                              void* d_out, int out_size, void* d_ws, size_t ws_size,
                              hipStream_t stream) {
    const int* x = (const int*)d_in[0];     // (B, C, L) int32
    const int* w = (const int*)d_in[1];     // (N, C) int32
    int* out = (int*)d_out;                 // (B, N) int32 values in [-128,127]

    int* acc     = (int*)d_ws;              // B*C ints = 2 MB
    int* partial = acc + (size_t)BB * CC;   // Z*B*N ints

    size_t accBytes = (size_t)BB * CC * 4;
    int Z = 8;                              // 10 MB total ws
    while (Z > 1 && ws_size < accBytes + (size_t)Z * BB * NN * 4) Z >>= 1;
    int kch = CC / Z;

    pool_kernel<<<PBLK, 256, 0, stream>>>(x, acc);

    dim3 g2(BB / TBB, (NN + TNN - 1) / TNN, Z);   // (4, 8, Z) = 256 blocks at Z=8
    gemm_kernel<<<g2, 256, 0, stream>>>(acc, w, partial, kch);

    epilogue_kernel<<<(BB * NN + 255) / 256, 256, 0, stream>>>(partial, out, Z);
}

// Round 11
// 199.759 us; speedup vs baseline: 1.1301x; 1.0345x over previous
//
#include <hip/hip_runtime.h>

// IntClassifier: sum-pool over L + dead_shift(4) -> int GEMM (i8 dot4, hi/lo split)
// -> dead_shift(11)+clamp -> int8 (as int32). B=256, C=2048, L=512, N=1000
//
// FINAL CONFIG (= round-7's measured 199.8us):
//  - pool: nt loads (r8 ablation: removing nt cost +26us), grid-wide sweep
//    (r9: contiguous-per-block cost +9.6us), bounds(256,8) -> 32 waves/CU
//    (r7: +5.5us over 5 waves/SIMD).
//  - GEMM/epilogue: plain cached loads (r10: nt here cost +6.8us — W is read
//    4x across b-tiles, partials are L2-resident after GEMM).
#define BB 256
#define CC 2048
#define LL 512
#define NN 1000
#define FINAL_SHIFT 4
#define FC_SHIFT 11

// GEMM tiling
#define TBB 64       // b per block
#define TNN 128      // n per block
#define BK 64        // k per LDS stage
#define NKQ 16       // BK/4 packed dwords per row
#define ASTR 36      // As row stride: 16 hi + 16 lo + 4 pad
#define WSTR 132     // Ws row stride: 128 + 4 pad

// Pool persistence: 2048 blocks x 16 sweeps; 4 rows per wave per sweep.
#define PBLK 2048
#define RPS  (PBLK * 16)        // rows per sweep: 4 waves x 4 rows x 2048 = 32768
#define PITER (BB * CC / RPS)   // 16 sweeps

typedef int v4i __attribute__((ext_vector_type(4)));

#if __has_builtin(__builtin_amdgcn_sdot4)
#define DOT4(a, b, c) __builtin_amdgcn_sdot4((a), (b), (c), false)
#else
static __device__ __forceinline__ int dot4_fb(int a, int b, int c) {
#pragma unroll
    for (int j = 0; j < 4; ++j) {
        int av = (a << (24 - 8 * j)) >> 24;
        int bv = (b << (24 - 8 * j)) >> 24;
        c += av * bv;
    }
    return c;
}
#define DOT4(a, b, c) dot4_fb((a), (b), (c))
#endif

__device__ __forceinline__ int dead_shift_i(int x, int shift) {
    int thr = 1 << shift;
    int ax = x < 0 ? -x : x;
    x = (ax >= thr) ? x : 0;
    return x >> shift;
}

// byte-pack helpers (byte j of result = k-value 4q+j)
__device__ __forceinline__ int pack_hi(int4 u) {
    return ((u.x >> 6) & 255) | (((u.y >> 6) & 255) << 8) |
           (((u.z >> 6) & 255) << 16) | (((u.w >> 6) & 255) << 24);
}
__device__ __forceinline__ int pack_lo(int4 u) {
    return (u.x & 63) | ((u.y & 63) << 8) | ((u.z & 63) << 16) | ((u.w & 63) << 24);
}
__device__ __forceinline__ int pack_b(int4 u) {
    return (u.x & 255) | ((u.y & 255) << 8) | ((u.z & 255) << 16) | ((u.w & 255) << 24);
}

// ---------------- Stage 1: persistent, pipelined sum-pool ----------------
// v[8] in flight (32 VGPR) + __launch_bounds__(256,8) -> VGPR<=64, 8 blocks/CU,
// all 2048 blocks resident (32 waves/CU). Next sweep's 8 nt-loads issue before
// the current sweep's shfl chain + store.
__global__ __launch_bounds__(256, 8) void pool_kernel(const int* __restrict__ x,
                                                      int* __restrict__ acc) {
    int wave = threadIdx.x >> 6;
    int lane = threadIdx.x & 63;
    int g = lane >> 4;                 // row within wave's quad
    int j = lane & 15;                 // lane within 16-lane row group

    long long rb = (long long)blockIdx.x * 16 + wave * 4;   // first sweep's row base

    v4i v[8];
    {
        const int* p = x + (rb + g) * (long long)LL + j * 4;
#pragma unroll
        for (int c = 0; c < 8; ++c) v[c] = __builtin_nontemporal_load((const v4i*)(p + c * 64));
    }

#pragma unroll
    for (int it = 0; it < PITER; ++it) {
        int s = 0;
#pragma unroll
        for (int c = 0; c < 8; ++c) s += v[c].x + v[c].y + v[c].z + v[c].w;

        // issue next sweep's loads before the dependent shfl/store tail
        long long rbn = rb + RPS;
        if (it + 1 < PITER) {
            const int* p = x + (rbn + g) * (long long)LL + j * 4;
#pragma unroll
            for (int c = 0; c < 8; ++c) v[c] = __builtin_nontemporal_load((const v4i*)(p + c * 64));
        }

        s += __shfl_xor(s, 1, 64);
        s += __shfl_xor(s, 2, 64);
        s += __shfl_xor(s, 4, 64);
        s += __shfl_xor(s, 8, 64);

        if (j == 0) acc[rb + g] = dead_shift_i(s, FINAL_SHIFT);
        rb = rbn;
    }
}

// ---------------- Stage 2: i8-dot4 GEMM, K-split partials ----------------
__global__ __launch_bounds__(256) void gemm_kernel(const int* __restrict__ acc,
                                                   const int* __restrict__ w,
                                                   int* __restrict__ partial,
                                                   int kch) {
    __shared__ int As[TBB][ASTR];    // [b][0..15]=hi dwords, [16..31]=lo dwords
    __shared__ int Ws[NKQ][WSTR];    // [kq][n] packed W dwords

    int b0 = blockIdx.x * TBB;
    int n0 = blockIdx.y * TNN;
    int kbase = blockIdx.z * kch;

    int t   = threadIdx.x;
    int tx4 = (t & 15) * 4;
    int ty4 = (t >> 4) * 4;

    int rH[4][8], rL[4][8];
#pragma unroll
    for (int bi = 0; bi < 4; ++bi)
#pragma unroll
        for (int j = 0; j < 8; ++j) { rH[bi][j] = 0; rL[bi][j] = 0; }

    for (int k0 = kbase; k0 < kbase + kch; k0 += BK) {
        {
            int b   = t >> 2;
            int kq0 = (t & 3) * 4;
            const int* src = acc + (long long)(b0 + b) * CC + k0 + kq0 * 4;
            int4 u0 = *(const int4*)(src + 0);
            int4 u1 = *(const int4*)(src + 4);
            int4 u2 = *(const int4*)(src + 8);
            int4 u3 = *(const int4*)(src + 12);
            *(int4*)&As[b][kq0]      = make_int4(pack_hi(u0), pack_hi(u1), pack_hi(u2), pack_hi(u3));
            *(int4*)&As[b][16 + kq0] = make_int4(pack_lo(u0), pack_lo(u1), pack_lo(u2), pack_lo(u3));
        }
        {
            int jq = t & 15;
            int ng = t >> 4;
#pragma unroll
            for (int rep = 0; rep < 8; ++rep) {
                int n  = rep * 16 + ng;
                int nn = n0 + n;
                int4 u = make_int4(0, 0, 0, 0);
                if (nn < NN) u = *(const int4*)(w + (long long)nn * CC + k0 + jq * 4);
                Ws[jq][n] = pack_b(u);
            }
        }
        __syncthreads();

#pragma unroll
        for (int q4 = 0; q4 < NKQ; q4 += 4) {
            int4 aH[4], aL[4];
#pragma unroll
            for (int bi = 0; bi < 4; ++bi) {
                aH[bi] = *(const int4*)&As[ty4 + bi][q4];
                aL[bi] = *(const int4*)&As[ty4 + bi][16 + q4];
            }
#pragma unroll
            for (int q = 0; q < 4; ++q) {
                int4 w0 = *(const int4*)&Ws[q4 + q][tx4];
                int4 w1 = *(const int4*)&Ws[q4 + q][64 + tx4];
#pragma unroll
                for (int bi = 0; bi < 4; ++bi) {
                    int ah = (q == 0) ? aH[bi].x : (q == 1) ? aH[bi].y
                           : (q == 2) ? aH[bi].z : aH[bi].w;
                    int al = (q == 0) ? aL[bi].x : (q == 1) ? aL[bi].y
                           : (q == 2) ? aL[bi].z : aL[bi].w;
                    rH[bi][0] = DOT4(ah, w0.x, rH[bi][0]);
                    rH[bi][1] = DOT4(ah, w0.y, rH[bi][1]);
                    rH[bi][2] = DOT4(ah, w0.z, rH[bi][2]);
                    rH[bi][3] = DOT4(ah, w0.w, rH[bi][3]);
                    rH[bi][4] = DOT4(ah, w1.x, rH[bi][4]);
                    rH[bi][5] = DOT4(ah, w1.y, rH[bi][5]);
                    rH[bi][6] = DOT4(ah, w1.z, rH[bi][6]);
                    rH[bi][7] = DOT4(ah, w1.w, rH[bi][7]);
                    rL[bi][0] = DOT4(al, w0.x, rL[bi][0]);
                    rL[bi][1] = DOT4(al, w0.y, rL[bi][1]);
                    rL[bi][2] = DOT4(al, w0.z, rL[bi][2]);
                    rL[bi][3] = DOT4(al, w0.w, rL[bi][3]);
                    rL[bi][4] = DOT4(al, w1.x, rL[bi][4]);
                    rL[bi][5] = DOT4(al, w1.y, rL[bi][5]);
                    rL[bi][6] = DOT4(al, w1.z, rL[bi][6]);
                    rL[bi][7] = DOT4(al, w1.w, rL[bi][7]);
                }
            }
        }
        __syncthreads();
    }

    long long base = (long long)blockIdx.z * BB * NN;
#pragma unroll
    for (int bi = 0; bi < 4; ++bi) {
        int b = b0 + ty4 + bi;
#pragma unroll
        for (int j = 0; j < 8; ++j) {
            int n = n0 + ((j < 4) ? (tx4 + j) : (64 + tx4 + (j - 4)));
            if (n < NN)
                partial[base + (long long)b * NN + n] = (rH[bi][j] << 6) + rL[bi][j];
        }
    }
}

// ---------------- Stage 3: reduce K-splits, dead_shift(11), clamp ----------------
__global__ __launch_bounds__(256) void epilogue_kernel(const int* __restrict__ partial,
                                                       int* __restrict__ out, int z) {
    int idx = blockIdx.x * 256 + threadIdx.x;
    if (idx >= BB * NN) return;
    int s = 0;
    for (int i = 0; i < z; ++i) s += partial[(long long)i * BB * NN + idx];
    int v = dead_shift_i(s, FC_SHIFT);
    v = min(127, max(-128, v));
    out[idx] = v;
}

extern "C" void kernel_launch(void* const* d_in, const int* in_sizes, int n_in,
                              void* d_out, int out_size, void* d_ws, size_t ws_size,
                              hipStream_t stream) {
    const int* x = (const int*)d_in[0];     // (B, C, L) int32
    const int* w = (const int*)d_in[1];     // (N, C) int32
    int* out = (int*)d_out;                 // (B, N) int32 values in [-128,127]

    int* acc     = (int*)d_ws;              // B*C ints = 2 MB
    int* partial = acc + (size_t)BB * CC;   // Z*B*N ints

    size_t accBytes = (size_t)BB * CC * 4;
    int Z = 8;                              // 10 MB total ws
    while (Z > 1 && ws_size < accBytes + (size_t)Z * BB * NN * 4) Z >>= 1;
    int kch = CC / Z;

    pool_kernel<<<PBLK, 256, 0, stream>>>(x, acc);

    dim3 g2(BB / TBB, (NN + TNN - 1) / TNN, Z);   // (4, 8, Z) = 256 blocks at Z=8
    gemm_kernel<<<g2, 256, 0, stream>>>(acc, w, partial, kch);

    epilogue_kernel<<<(BB * NN + 255) / 256, 256, 0, stream>>>(partial, out, Z);
}